// Round 1
// baseline (1108.004 us; speedup 1.0000x reference)
//
#include <hip/hip_runtime.h>

// BlockDiagonalChannelAttention: B=4, C=128, H=W=224, PH=PW=7 -> Hh=Ww=32, M=1024, P=49
// One block per patch (bm = b*1024 + hh*32 + ww), 512 threads, 2 blocks/CU.

#define CCH 128
#define SF_STR 60    // sF row stride in floats: 7 slots x 8 + mu at [56]; 240B rows ->
                     // 240 mod 128 = 112 => period-8 bank walk, conflict-free b128 reads
#define SA_STR 136   // sA row stride in bf16: 272B rows -> 16B-aligned, period-8 banks

typedef __attribute__((ext_vector_type(8))) unsigned short ushort8v;

static __device__ __forceinline__ unsigned short f2bf(float f) {
    unsigned u = __builtin_bit_cast(unsigned, f);
    u = (u + 0x7FFFu + ((u >> 16) & 1u)) >> 16;   // RNE
    return (unsigned short)u;
}
static __device__ __forceinline__ float bf2f(unsigned short h) {
    return __builtin_bit_cast(float, ((unsigned)h) << 16);
}

__global__ __launch_bounds__(512, 4)
void bdca_kernel(const float* __restrict__ x, const float* __restrict__ betap,
                 float* __restrict__ out, float* __restrict__ sc_out,
                 float* __restrict__ cov_out, float* __restrict__ ec_out)
{
    __shared__ float sF[CCH * SF_STR];            // 30,720 B (mu_c lives at slot 56)
    __shared__ unsigned short sA[CCH * SA_STR];   // 34,816 B  (total = 65,536 B)

    const int bm = blockIdx.x;
    const int b  = bm >> 10;
    const int hh = (bm >> 5) & 31;
    const int ww = bm & 31;
    const int t  = threadIdx.x;
    const float beta = betap[0];

    const float* xpatch = x + (size_t)b * (CCH * 50176) + (hh * 7) * 224 + (ww * 7);

    // ---- stage patch into LDS (slot layout) ----
    for (int r = t; r < CCH * 7; r += 512) {
        int c = r / 7, i = r - c * 7;
        const float* src = xpatch + (size_t)c * 50176 + i * 224;
        float* dst = &sF[c * SF_STR + i * 8];
        #pragma unroll
        for (int j = 0; j < 7; ++j) dst[j] = src[j];
    }
    __syncthreads();

    // ---- per-channel mean mu_c -> sF[c*SF_STR + 56] ----
    if (t < CCH) {
        const float* row = &sF[t * SF_STR];
        float s = 0.f;
        #pragma unroll
        for (int sl = 0; sl < 7; ++sl) {
            #pragma unroll
            for (int k = 0; k < 7; ++k) s += row[sl * 8 + k];
        }
        sF[t * SF_STR + 56] = s * (1.f / 49.f);
    }
    __syncthreads();

    // ---- G = flat . flat^T, 4x8 register tile per thread ----
    const int rg = t >> 4;   // 0..31, rows c = rg + 32*i
    const int cg = t & 15;   // cols d = cg + 16*j
    float g[4][8];
    #pragma unroll
    for (int i = 0; i < 4; ++i)
        #pragma unroll
        for (int j = 0; j < 8; ++j) g[i][j] = 0.f;

    #pragma unroll 1
    for (int sl = 0; sl < 7; ++sl) {
        float av[4][7];
        #pragma unroll
        for (int i = 0; i < 4; ++i) {
            const float* ap = &sF[(rg + 32 * i) * SF_STR + sl * 8];
            float4 a4 = *(const float4*)ap;
            float2 a2 = *(const float2*)(ap + 4);
            float  a6 = ap[6];
            av[i][0] = a4.x; av[i][1] = a4.y; av[i][2] = a4.z; av[i][3] = a4.w;
            av[i][4] = a2.x; av[i][5] = a2.y; av[i][6] = a6;
        }
        #pragma unroll
        for (int j = 0; j < 8; ++j) {
            const float* bp = &sF[(cg + 16 * j) * SF_STR + sl * 8];
            float4 b4 = *(const float4*)bp;
            float2 b2 = *(const float2*)(bp + 4);
            float  b6 = bp[6];
            float bv[7] = {b4.x, b4.y, b4.z, b4.w, b2.x, b2.y, b6};
            #pragma unroll
            for (int i = 0; i < 4; ++i)
                #pragma unroll
                for (int k = 0; k < 7; ++k)
                    g[i][j] = fmaf(av[i][k], bv[k], g[i][j]);
        }
    }

    // ---- softmax rows (16-lane butterfly), write Sc & cov, stage A=Sc+0.5*cov (bf16) ----
    const size_t scbase = (size_t)bm * (CCH * CCH);
    float mud[8];
    #pragma unroll
    for (int j = 0; j < 8; ++j) mud[j] = sF[(cg + 16 * j) * SF_STR + 56];

    #pragma unroll
    for (int i = 0; i < 4; ++i) {
        const int c = rg + 32 * i;
        float m = g[i][0];
        #pragma unroll
        for (int j = 1; j < 8; ++j) m = fmaxf(m, g[i][j]);
        #pragma unroll
        for (int msk = 1; msk <= 8; msk <<= 1) m = fmaxf(m, __shfl_xor(m, msk, 64));
        float e[8];
        float s = 0.f;
        #pragma unroll
        for (int j = 0; j < 8; ++j) { e[j] = __expf(g[i][j] - m); s += e[j]; }
        #pragma unroll
        for (int msk = 1; msk <= 8; msk <<= 1) s += __shfl_xor(s, msk, 64);
        const float rinv = 1.f / s;
        const float muc  = sF[c * SF_STR + 56];
        const size_t rowb = scbase + (size_t)c * CCH;
        #pragma unroll
        for (int j = 0; j < 8; ++j) {
            const int d = cg + 16 * j;
            const float sc = e[j] * rinv;
            const float cv = g[i][j] * (1.f / 49.f) - muc * mud[j];
            sc_out[rowb + d]  = sc;
            cov_out[rowb + d] = cv;
            sA[c * SA_STR + d] = f2bf(fmaf(0.5f, cv, sc));
        }
    }
    __syncthreads();

    // ---- Ec = A . flat ; fold + out = x*(beta*Ec + x) ----
    if (t < 448) {
        const int dq  = t & 3;          // d-quarter (4 lanes per (cg2,pg))
        const int cg2 = (t >> 2) & 15;  // rows c = cg2 + 16*i
        const int pg  = t >> 6;         // 0..6 : patch row, cols p = pg*7 + k
        float acc[8][7];
        #pragma unroll
        for (int i = 0; i < 8; ++i)
            #pragma unroll
            for (int k = 0; k < 7; ++k) acc[i][k] = 0.f;

        #pragma unroll 1
        for (int jc = 0; jc < 4; ++jc) {
            const int d0 = dq * 32 + jc * 8;
            ushort8v av[8];
            #pragma unroll
            for (int i = 0; i < 8; ++i)
                av[i] = *(const ushort8v*)&sA[(cg2 + 16 * i) * SA_STR + d0];
            #pragma unroll
            for (int q = 0; q < 8; ++q) {
                const float* fp = &sF[(d0 + q) * SF_STR + pg * 8];
                float4 f4 = *(const float4*)fp;
                float2 f2 = *(const float2*)(fp + 4);
                float  f6 = fp[6];
                float fv[7] = {f4.x, f4.y, f4.z, f4.w, f2.x, f2.y, f6};
                #pragma unroll
                for (int i = 0; i < 8; ++i) {
                    const float aval = bf2f(av[i][q]);
                    #pragma unroll
                    for (int k = 0; k < 7; ++k)
                        acc[i][k] = fmaf(aval, fv[k], acc[i][k]);
                }
            }
        }
        // combine the four d-quarters (butterfly over lanes t^1, t^2)
        #pragma unroll
        for (int i = 0; i < 8; ++i) {
            #pragma unroll
            for (int k = 0; k < 7; ++k) {
                float v = acc[i][k];
                v += __shfl_xor(v, 1, 64);
                v += __shfl_xor(v, 2, 64);
                acc[i][k] = v;
            }
        }

        // each dq lane writes 2 of the 8 c-rows
        #pragma unroll
        for (int i = 0; i < 8; ++i) {
            if ((i >> 1) == dq) {
                const int c = cg2 + 16 * i;
                const float* xrow = &sF[c * SF_STR + pg * 8];
                const size_t gaddr =
                    ((size_t)(b * CCH + c) * 224 + (hh * 7 + pg)) * 224 + (ww * 7);
                #pragma unroll
                for (int k = 0; k < 7; ++k) {
                    const float ec = acc[i][k];
                    const float xv = xrow[k];
                    ec_out[gaddr + k] = ec;
                    out[gaddr + k]    = xv * fmaf(beta, ec, xv);
                }
            }
        }
    }
}

extern "C" void kernel_launch(void* const* d_in, const int* in_sizes, int n_in,
                              void* d_out, int out_size, void* d_ws, size_t ws_size,
                              hipStream_t stream)
{
    const float* x    = (const float*)d_in[0];
    const float* beta = (const float*)d_in[1];
    float* out = (float*)d_out;
    float* sc  = out + 25690112;   // 4*128*224*224
    float* cov = sc  + 67108864;   // 4*1024*128*128
    float* ec  = cov + 67108864;
    bdca_kernel<<<dim3(4096), dim3(512), 0, stream>>>(x, beta, out, sc, cov, ec);
}

// Round 2
// 1075.710 us; speedup vs baseline: 1.0300x; 1.0300x over previous
//
#include <hip/hip_runtime.h>

// BlockDiagonalChannelAttention: B=4, C=128, H=W=224, PH=PW=7 -> Hh=Ww=32, M=1024, P=49
// One block per patch (bm = b*1024 + hh*32 + ww), 512 threads, 2 blocks/CU.
// R2: XCD-contiguous block swizzle + nontemporal sc/cov stores + sF XOR bank swizzle.

#define CCH 128
#define SF_STR 64    // sF row stride in floats (256B rows) + XOR swizzle (see sfx)
#define SA_STR 136   // sA row stride in bf16: 272B rows -> 16B-aligned, period-8 banks

typedef __attribute__((ext_vector_type(8))) unsigned short ushort8v;

static __device__ __forceinline__ unsigned short f2bf(float f) {
    unsigned u = __builtin_bit_cast(unsigned, f);
    u = (u + 0x7FFFu + ((u >> 16) & 1u)) >> 16;   // RNE
    return (unsigned short)u;
}
static __device__ __forceinline__ float bf2f(unsigned short h) {
    return __builtin_bit_cast(float, ((unsigned)h) << 16);
}
// swizzled float-index into sF: banks depend only on swizzled col (row*64 == 0 mod 32),
// key mixes row low bits and row>>5 so rows spaced 1 AND rows spaced 32 get distinct banks
static __device__ __forceinline__ int sfx(int row, int col) {
    return (row << 6) + (col ^ (((row ^ (row >> 5)) & 7) << 2));
}

__global__ __launch_bounds__(512, 4)
void bdca_kernel(const float* __restrict__ x, const float* __restrict__ betap,
                 float* __restrict__ out, float* __restrict__ sc_out,
                 float* __restrict__ cov_out, float* __restrict__ ec_out)
{
    __shared__ float sF[CCH * SF_STR];            // 32,768 B (mu_c lives at col 56)
    __shared__ unsigned short sA[CCH * SA_STR];   // 34,816 B  (total = 67,584 B)

    // XCD-contiguous swizzle: each XCD gets a contiguous bm chunk so adjacent-ww
    // patches (sharing 64B lines of x/out/ec) hit the same L2.
    const int bid = blockIdx.x;
    const int bm  = (bid & 7) * 512 + (bid >> 3);
    const int b  = bm >> 10;
    const int hh = (bm >> 5) & 31;
    const int ww = bm & 31;
    const int t  = threadIdx.x;
    const float beta = betap[0];

    const float* xpatch = x + (size_t)b * (CCH * 50176) + (hh * 7) * 224 + (ww * 7);

    // ---- stage patch into LDS (swizzled slot layout) ----
    for (int r = t; r < CCH * 7; r += 512) {
        int c = r / 7, i = r - c * 7;
        const float* src = xpatch + (size_t)c * 50176 + i * 224;
        float* dA = &sF[sfx(c, i * 8)];
        float* dB = &sF[sfx(c, i * 8 + 4)];
        dA[0] = src[0]; dA[1] = src[1]; dA[2] = src[2]; dA[3] = src[3];
        dB[0] = src[4]; dB[1] = src[5]; dB[2] = src[6];
    }
    __syncthreads();

    // ---- per-channel mean mu_c -> swizzled col 56 ----
    if (t < CCH) {
        float s = 0.f;
        #pragma unroll
        for (int sl = 0; sl < 7; ++sl) {
            const float* pA = &sF[sfx(t, sl * 8)];
            const float* pB = &sF[sfx(t, sl * 8 + 4)];
            s += pA[0] + pA[1] + pA[2] + pA[3] + pB[0] + pB[1] + pB[2];
        }
        sF[sfx(t, 56)] = s * (1.f / 49.f);
    }
    __syncthreads();

    // ---- G = flat . flat^T, 4x8 register tile per thread ----
    const int rg = t >> 4;   // 0..31, rows c = rg + 32*i
    const int cg = t & 15;   // cols d = cg + 16*j
    float g[4][8];
    #pragma unroll
    for (int i = 0; i < 4; ++i)
        #pragma unroll
        for (int j = 0; j < 8; ++j) g[i][j] = 0.f;

    #pragma unroll 1
    for (int sl = 0; sl < 7; ++sl) {
        float av[4][7];
        #pragma unroll
        for (int i = 0; i < 4; ++i) {
            const float* pA = &sF[sfx(rg + 32 * i, sl * 8)];
            const float* pB = &sF[sfx(rg + 32 * i, sl * 8 + 4)];
            float4 a4 = *(const float4*)pA;
            float2 a2 = *(const float2*)pB;
            float  a6 = pB[2];
            av[i][0] = a4.x; av[i][1] = a4.y; av[i][2] = a4.z; av[i][3] = a4.w;
            av[i][4] = a2.x; av[i][5] = a2.y; av[i][6] = a6;
        }
        #pragma unroll
        for (int j = 0; j < 8; ++j) {
            const float* pA = &sF[sfx(cg + 16 * j, sl * 8)];
            const float* pB = &sF[sfx(cg + 16 * j, sl * 8 + 4)];
            float4 b4 = *(const float4*)pA;
            float2 b2 = *(const float2*)pB;
            float  b6 = pB[2];
            float bv[7] = {b4.x, b4.y, b4.z, b4.w, b2.x, b2.y, b6};
            #pragma unroll
            for (int i = 0; i < 4; ++i)
                #pragma unroll
                for (int k = 0; k < 7; ++k)
                    g[i][j] = fmaf(av[i][k], bv[k], g[i][j]);
        }
    }

    // ---- softmax rows (16-lane butterfly), write Sc & cov (nontemporal),
    //      stage A = Sc + 0.5*cov (bf16) ----
    const size_t scbase = (size_t)bm * (CCH * CCH);
    float mud[8];
    #pragma unroll
    for (int j = 0; j < 8; ++j) mud[j] = sF[sfx(cg + 16 * j, 56)];

    #pragma unroll
    for (int i = 0; i < 4; ++i) {
        const int c = rg + 32 * i;
        float m = g[i][0];
        #pragma unroll
        for (int j = 1; j < 8; ++j) m = fmaxf(m, g[i][j]);
        #pragma unroll
        for (int msk = 1; msk <= 8; msk <<= 1) m = fmaxf(m, __shfl_xor(m, msk, 64));
        float e[8];
        float s = 0.f;
        #pragma unroll
        for (int j = 0; j < 8; ++j) { e[j] = __expf(g[i][j] - m); s += e[j]; }
        #pragma unroll
        for (int msk = 1; msk <= 8; msk <<= 1) s += __shfl_xor(s, msk, 64);
        const float rinv = 1.f / s;
        const float muc  = sF[sfx(c, 56)];
        const size_t rowb = scbase + (size_t)c * CCH;
        #pragma unroll
        for (int j = 0; j < 8; ++j) {
            const int d = cg + 16 * j;
            const float sc = e[j] * rinv;
            const float cv = g[i][j] * (1.f / 49.f) - muc * mud[j];
            __builtin_nontemporal_store(sc, &sc_out[rowb + d]);
            __builtin_nontemporal_store(cv, &cov_out[rowb + d]);
            sA[c * SA_STR + d] = f2bf(fmaf(0.5f, cv, sc));
        }
    }
    __syncthreads();

    // ---- Ec = A . flat ; fold + out = x*(beta*Ec + x) ----
    if (t < 448) {
        const int dq  = t & 3;          // d-quarter (4 lanes per (cg2,pg))
        const int cg2 = (t >> 2) & 15;  // rows c = cg2 + 16*i
        const int pg  = t >> 6;         // 0..6 : patch row, cols p = pg*7 + k
        float acc[8][7];
        #pragma unroll
        for (int i = 0; i < 8; ++i)
            #pragma unroll
            for (int k = 0; k < 7; ++k) acc[i][k] = 0.f;

        #pragma unroll 1
        for (int jc = 0; jc < 4; ++jc) {
            const int d0 = dq * 32 + jc * 8;
            ushort8v av[8];
            #pragma unroll
            for (int i = 0; i < 8; ++i)
                av[i] = *(const ushort8v*)&sA[(cg2 + 16 * i) * SA_STR + d0];
            #pragma unroll
            for (int q = 0; q < 8; ++q) {
                const float* pA = &sF[sfx(d0 + q, pg * 8)];
                const float* pB = &sF[sfx(d0 + q, pg * 8 + 4)];
                float4 f4 = *(const float4*)pA;
                float2 f2 = *(const float2*)pB;
                float  f6 = pB[2];
                float fv[7] = {f4.x, f4.y, f4.z, f4.w, f2.x, f2.y, f6};
                #pragma unroll
                for (int i = 0; i < 8; ++i) {
                    const float aval = bf2f(av[i][q]);
                    #pragma unroll
                    for (int k = 0; k < 7; ++k)
                        acc[i][k] = fmaf(aval, fv[k], acc[i][k]);
                }
            }
        }
        // combine the four d-quarters (butterfly over lanes t^1, t^2)
        #pragma unroll
        for (int i = 0; i < 8; ++i) {
            #pragma unroll
            for (int k = 0; k < 7; ++k) {
                float v = acc[i][k];
                v += __shfl_xor(v, 1, 64);
                v += __shfl_xor(v, 2, 64);
                acc[i][k] = v;
            }
        }

        // each dq lane writes 2 of the 8 c-rows
        #pragma unroll
        for (int i = 0; i < 8; ++i) {
            if ((i >> 1) == dq) {
                const int c = cg2 + 16 * i;
                const float* xA = &sF[sfx(c, pg * 8)];
                const float* xB = &sF[sfx(c, pg * 8 + 4)];
                const size_t gaddr =
                    ((size_t)(b * CCH + c) * 224 + (hh * 7 + pg)) * 224 + (ww * 7);
                #pragma unroll
                for (int k = 0; k < 7; ++k) {
                    const float ec = acc[i][k];
                    const float xv = (k < 4) ? xA[k] : xB[k - 4];
                    ec_out[gaddr + k] = ec;
                    out[gaddr + k]    = xv * fmaf(beta, ec, xv);
                }
            }
        }
    }
}

extern "C" void kernel_launch(void* const* d_in, const int* in_sizes, int n_in,
                              void* d_out, int out_size, void* d_ws, size_t ws_size,
                              hipStream_t stream)
{
    const float* x    = (const float*)d_in[0];
    const float* beta = (const float*)d_in[1];
    float* out = (float*)d_out;
    float* sc  = out + 25690112;   // 4*128*224*224
    float* cov = sc  + 67108864;   // 4*1024*128*128
    float* ec  = cov + 67108864;
    bdca_kernel<<<dim3(4096), dim3(512), 0, stream>>>(x, beta, out, sc, cov, ec);
}

// Round 3
// 924.799 us; speedup vs baseline: 1.1981x; 1.1632x over previous
//
#include <hip/hip_runtime.h>

// BlockDiagonalChannelAttention: B=4, C=128, H=W=224, PH=PW=7 -> Hh=Ww=32, M=1024, P=49
// One block per patch, 512 threads (8 waves), 2 blocks/CU.
// R3: both GEMMs (G = flat.flatT, Ec = A.flat) moved to mfma_f32_16x16x32_bf16.
//     LDS: flatB (128x64 bf16, K-padded), flatT (64x128 bf16), sA (128x128 bf16),
//     all XOR-swizzled for conflict-free ds_read_b128 fragment loads. 66 KB total.

#define CCH 128

typedef __attribute__((ext_vector_type(8))) short short8v;   // bf16x8 MFMA fragment
typedef __attribute__((ext_vector_type(4))) float f32x4;     // MFMA accumulator

static __device__ __forceinline__ unsigned short f2bf(float f) {
    unsigned u = __builtin_bit_cast(unsigned, f);
    u = (u + 0x7FFFu + ((u >> 16) & 1u)) >> 16;   // RNE
    return (unsigned short)u;
}

// element-index helpers; XOR on element bits 3..5 spreads rows across 16B bank slots
static __device__ __forceinline__ int fbx(int c, int p) {   // flatB: 128 x 64
    return (c << 6) + (p ^ ((c & 7) << 3));
}
static __device__ __forceinline__ int ftx(int p, int d) {   // flatT: 64 x 128
    return (p << 7) + (d ^ ((p & 7) << 3));
}
static __device__ __forceinline__ int sax(int c, int d) {   // sA: 128 x 128
    return (c << 7) + (d ^ ((c & 7) << 3));
}

__global__ __launch_bounds__(512, 4)
void bdca_kernel(const float* __restrict__ x, const float* __restrict__ betap,
                 float* __restrict__ out, float* __restrict__ sc_out,
                 float* __restrict__ cov_out, float* __restrict__ ec_out)
{
    __shared__ __align__(16) unsigned short sFB[CCH * 64];   // 16,384 B (p 49..63 zero)
    __shared__ __align__(16) unsigned short sFT[64 * CCH];   // 16,384 B (rows 49..63 zero)
    __shared__ __align__(16) unsigned short sAm[CCH * CCH];  // 32,768 B
    __shared__ float smu[CCH];                               //    512 B  (total 66,048 B)

    const int bid = blockIdx.x;
    const int bm  = (bid & 7) * 512 + (bid >> 3);   // XCD-contiguous swizzle
    const int b  = bm >> 10;
    const int hh = (bm >> 5) & 31;
    const int ww = bm & 31;
    const int t  = threadIdx.x;
    const int lane = t & 63;
    const int w    = t >> 6;          // wave 0..7 -> owns rows 16w..16w+15
    const int lr   = lane & 15;       // fragment row/col index
    const int lk   = lane >> 4;       // fragment k-chunk selector
    const float beta = betap[0];

    // ---- phase 0: zero bf16 tiles (padding must be 0) + smu ----
    {
        short8v z = (short8v){0, 0, 0, 0, 0, 0, 0, 0};
        short8v* pB = (short8v*)sFB;   // 1024 vectors
        short8v* pT = (short8v*)sFT;   // 1024 vectors
        pB[t] = z; pB[t + 512] = z;
        pT[t] = z; pT[t + 512] = z;
        if (t < CCH) smu[t] = 0.f;
    }
    __syncthreads();

    // ---- phase 1: stage patch -> bf16 flatB + flatT, accumulate channel sums ----
    const float* xpatch = x + (size_t)b * (CCH * 50176) + (hh * 7) * 224 + (ww * 7);
    for (int r = t; r < CCH * 7; r += 512) {
        const int c = r / 7, i = r - c * 7;
        const float* src = xpatch + (size_t)c * 50176 + i * 224;
        float4 a4 = *(const float4*)src;
        float2 a2 = *(const float2*)(src + 4);
        float  a6 = src[6];
        float v[7] = {a4.x, a4.y, a4.z, a4.w, a2.x, a2.y, a6};
        const int p0 = i * 7;
        #pragma unroll
        for (int j = 0; j < 7; ++j) {
            const unsigned short h = f2bf(v[j]);
            sFB[fbx(c, p0 + j)] = h;
            sFT[ftx(p0 + j, c)] = h;
        }
        atomicAdd(&smu[c], v[0] + v[1] + v[2] + v[3] + v[4] + v[5] + v[6]);
    }
    __syncthreads();

    // ---- phase 2: G = flat . flatT via MFMA (wave w: rows 16w..16w+15, all 8 d-tiles)
    // A-frag: lane holds row 16w+lr, k = lk*8+j (+32s); B-frag: col 16jt+lr, same k.
    short8v afrag[2];
    #pragma unroll
    for (int s = 0; s < 2; ++s)
        afrag[s] = *(const short8v*)&sFB[fbx(16 * w + lr, s * 32 + lk * 8)];
    f32x4 acc[8];
    #pragma unroll
    for (int jt = 0; jt < 8; ++jt) acc[jt] = (f32x4){0.f, 0.f, 0.f, 0.f};
    #pragma unroll
    for (int jt = 0; jt < 8; ++jt) {
        #pragma unroll
        for (int s = 0; s < 2; ++s) {
            short8v bfrag = *(const short8v*)&sFB[fbx(16 * jt + lr, s * 32 + lk * 8)];
            acc[jt] = __builtin_amdgcn_mfma_f32_16x16x32_bf16(afrag[s], bfrag, acc[jt], 0, 0, 0);
        }
    }

    // ---- phase 3: softmax + cov; write sc/cov (nontemporal); stage A = Sc+0.5cov ----
    // C/D layout: col = lane&15 (+16jt), row = (lane>>4)*4 + reg (+16w)
    const size_t scbase = (size_t)bm * (CCH * CCH);
    float mud[8];
    #pragma unroll
    for (int jt = 0; jt < 8; ++jt) mud[jt] = smu[16 * jt + lr] * (1.f / 49.f);

    #pragma unroll
    for (int r = 0; r < 4; ++r) {
        const int c = 16 * w + lk * 4 + r;
        float gv[8];
        #pragma unroll
        for (int jt = 0; jt < 8; ++jt) gv[jt] = acc[jt][r];
        float m = gv[0];
        #pragma unroll
        for (int jt = 1; jt < 8; ++jt) m = fmaxf(m, gv[jt]);
        #pragma unroll
        for (int msk = 1; msk <= 8; msk <<= 1) m = fmaxf(m, __shfl_xor(m, msk, 64));
        float e[8];
        float s = 0.f;
        #pragma unroll
        for (int jt = 0; jt < 8; ++jt) { e[jt] = __expf(gv[jt] - m); s += e[jt]; }
        #pragma unroll
        for (int msk = 1; msk <= 8; msk <<= 1) s += __shfl_xor(s, msk, 64);
        const float rinv = 1.f / s;
        const float muc  = smu[c] * (1.f / 49.f);
        const size_t rowb = scbase + (size_t)c * CCH;
        #pragma unroll
        for (int jt = 0; jt < 8; ++jt) {
            const int d = 16 * jt + lr;
            const float sc = e[jt] * rinv;
            const float cv = gv[jt] * (1.f / 49.f) - muc * mud[jt];
            __builtin_nontemporal_store(sc, &sc_out[rowb + d]);
            __builtin_nontemporal_store(cv, &cov_out[rowb + d]);
            sAm[sax(c, d)] = f2bf(fmaf(0.5f, cv, sc));
        }
    }
    __syncthreads();

    // ---- phase 4: Ec = A . flat via MFMA (wave w: rows 16w..16w+15, 4 p-tiles) ----
    // A-frag: row 16w+lr of sA, k=d; B-frag: col p=16nt+lr from flatT rows, k=d.
    short8v aA[4];
    #pragma unroll
    for (int ks = 0; ks < 4; ++ks)
        aA[ks] = *(const short8v*)&sAm[sax(16 * w + lr, ks * 32 + lk * 8)];
    f32x4 accE[4];
    #pragma unroll
    for (int nt = 0; nt < 4; ++nt) accE[nt] = (f32x4){0.f, 0.f, 0.f, 0.f};
    #pragma unroll
    for (int nt = 0; nt < 4; ++nt) {
        #pragma unroll
        for (int ks = 0; ks < 4; ++ks) {
            short8v bfr = *(const short8v*)&sFT[ftx(16 * nt + lr, ks * 32 + lk * 8)];
            accE[nt] = __builtin_amdgcn_mfma_f32_16x16x32_bf16(aA[ks], bfr, accE[nt], 0, 0, 0);
        }
    }

    // ---- phase 5: epilogue — fold, re-read x (L2-hot), write ec & out ----
    // lane holds rows c = 16w + lk*4 + reg, col p = 16nt + lr (valid iff p < 49)
    {
        const int cbase = 16 * w + lk * 4;
        unsigned ga[4][4];
        float    xv[4][4];
        #pragma unroll
        for (int nt = 0; nt < 4; ++nt) {
            const int p = 16 * nt + lr;
            const bool valid = (p < 49);
            const int pi = p / 7;
            const int pj = p - pi * 7;
            #pragma unroll
            for (int r = 0; r < 4; ++r) {
                const int c = cbase + r;
                const unsigned a =
                    ((unsigned)(b * CCH + c) * 224 + (unsigned)(hh * 7 + pi)) * 224
                    + (unsigned)(ww * 7 + pj);
                ga[nt][r] = a;
                if (valid) xv[nt][r] = x[a];
            }
        }
        #pragma unroll
        for (int nt = 0; nt < 4; ++nt) {
            const int p = 16 * nt + lr;
            if (p < 49) {
                #pragma unroll
                for (int r = 0; r < 4; ++r) {
                    const float ec = accE[nt][r];
                    const float v  = xv[nt][r];
                    ec_out[ga[nt][r]] = ec;
                    out[ga[nt][r]]    = v * fmaf(beta, ec, v);
                }
            }
        }
    }
}

extern "C" void kernel_launch(void* const* d_in, const int* in_sizes, int n_in,
                              void* d_out, int out_size, void* d_ws, size_t ws_size,
                              hipStream_t stream)
{
    const float* x    = (const float*)d_in[0];
    const float* beta = (const float*)d_in[1];
    float* out = (float*)d_out;
    float* sc  = out + 25690112;   // 4*128*224*224
    float* cov = sc  + 67108864;   // 4*1024*128*128
    float* ec  = cov + 67108864;
    bdca_kernel<<<dim3(4096), dim3(512), 0, stream>>>(x, beta, out, sc, cov, ec);
}